// Round 6
// baseline (1726.114 us; speedup 1.0000x reference)
//
#include <hip/hip_runtime.h>
#include <math.h>

// Problem constants
#define V_  8185
#define E_  353
#define H_  191
#define FH_ 764
#define Z_  13
#define T_  25
#define START_ 19
#define VP_ 8192
#define NTL 64      // logits col-tiles (128 cols each)
#define RKS 192     // padded k-stride of transposed rk (16B-aligned float4)

__device__ __forceinline__ float sigf(float x) { return 1.0f / (1.0f + expf(-x)); }

// ---------------------------------------------------------------------------
// One-time weight prep (merged): pad out_w (191x8185)->WP(191x8192) and
// transpose inf_rk/gen_rk (191x764) -> rkT[2][764][192] (zero pad k=191).
// ---------------------------------------------------------------------------
__global__ __launch_bounds__(256) void prep_w(const float* __restrict__ ow,
                                              const float* __restrict__ rkA,
                                              const float* __restrict__ rkB,
                                              float* __restrict__ WP,
                                              float* __restrict__ rkT) {
  int i = blockIdx.x * 256 + threadIdx.x;
  if (i < H_ * VP_) {
    int k = i >> 13;            // row (VP_=8192=2^13)
    int j = i & (VP_ - 1);      // col
    WP[i] = (j < V_) ? ow[(size_t)k * V_ + j] : 0.0f;
  } else {
    int i2 = i - H_ * VP_;
    if (i2 < 2 * FH_ * RKS) {
      int w = i2 / (FH_ * RKS), rem = i2 - w * (FH_ * RKS);
      int col4 = rem / RKS, k = rem - col4 * RKS;
      const float* src = w ? rkB : rkA;
      rkT[i2] = (k < H_) ? src[(size_t)k * FH_ + col4] : 0.0f;
    }
  }
}

// ---------------------------------------------------------------------------
// C[M][764] = A_rows[M][353] @ W[353][764]   (round-0 proven version)
// mode 0: A row m = emb[m]                      (EK = emb @ gen_k, M=V)
// mode 1: A row m=(t*B+b) = emb[inputs[b*T+t]]  (XK, M=T*B)
// ---------------------------------------------------------------------------
__global__ __launch_bounds__(256) void gemm_ew(const float* __restrict__ emb,
                                               const float* __restrict__ W,
                                               float* __restrict__ C, int M,
                                               const int* __restrict__ inputs,
                                               int mode, int B) {
  __shared__ __align__(16) float AT[E_ * 16];
  const int tid = threadIdx.x;
  const int n0 = blockIdx.x * 256;
  const int m0 = blockIdx.y * 16;
  for (int i = tid; i < 16 * E_; i += 256) {
    int r = i / E_, k = i - r * E_;
    int m = m0 + r;
    float v = 0.0f;
    if (m < M) {
      int row;
      if (mode == 0) row = m;
      else { int t = m / B, b = m - t * B; row = inputs[b * T_ + t]; }
      v = emb[(size_t)row * E_ + k];
    }
    AT[k * 16 + r] = v;
  }
  __syncthreads();
  const int lane = tid & 63;
  const int w4 = (tid >> 6) * 4;
  const int j = n0 + lane * 4;
  if (j >= FH_) return;  // 764 % 4 == 0: lanes are fully valid or fully out
  float4 c0 = {0,0,0,0}, c1 = {0,0,0,0}, c2 = {0,0,0,0}, c3 = {0,0,0,0};
  const float* wc = W + j;
  const float* at = AT + w4;
  for (int k = 0; k < E_; ++k) {
    float4 wv = *(const float4*)(wc + (size_t)k * FH_);
    float4 a  = *(const float4*)(at + k * 16);
    c0.x = fmaf(a.x, wv.x, c0.x); c0.y = fmaf(a.x, wv.y, c0.y);
    c0.z = fmaf(a.x, wv.z, c0.z); c0.w = fmaf(a.x, wv.w, c0.w);
    c1.x = fmaf(a.y, wv.x, c1.x); c1.y = fmaf(a.y, wv.y, c1.y);
    c1.z = fmaf(a.y, wv.z, c1.z); c1.w = fmaf(a.y, wv.w, c1.w);
    c2.x = fmaf(a.z, wv.x, c2.x); c2.y = fmaf(a.z, wv.y, c2.y);
    c2.z = fmaf(a.z, wv.z, c2.z); c2.w = fmaf(a.z, wv.w, c2.w);
    c3.x = fmaf(a.w, wv.x, c3.x); c3.y = fmaf(a.w, wv.y, c3.y);
    c3.z = fmaf(a.w, wv.z, c3.z); c3.w = fmaf(a.w, wv.w, c3.w);
  }
  const int mb = m0 + w4;
  if (mb + 0 < M) *(float4*)(C + (size_t)(mb + 0) * FH_ + j) = c0;
  if (mb + 1 < M) *(float4*)(C + (size_t)(mb + 1) * FH_ + j) = c1;
  if (mb + 2 < M) *(float4*)(C + (size_t)(mb + 2) * FH_ + j) = c2;
  if (mb + 3 < M) *(float4*)(C + (size_t)(mb + 3) * FH_ + j) = c3;
}

// ---------------------------------------------------------------------------
// One LSTM step. 8-row blocks: grid (24, B/8) = 768 blocks -> 3 blocks/CU
// (was 1.5 at 16-row blocks; these kernels are latency-bound, TLP is the fix).
//  - rk slice staged via coalesced float4 from rkT (round-4 proven)
//  - dot: 1 row/thread, k-ascending chain -> bitwise == previous rounds
//  - decoder pv argmax-reduce parallelized: 16-iter x 4 chunks + combine
//    (chunk-ascending combine keeps max-with-lowest-index exact)
// ---------------------------------------------------------------------------
__global__ __launch_bounds__(256) void lstm_step(const float* __restrict__ xk,
                                                 const float* __restrict__ rkT,
                                                 const float* __restrict__ bias,
                                                 const float* __restrict__ h_in,
                                                 const float* __restrict__ c_in,
                                                 float* __restrict__ h_out,
                                                 float* __restrict__ c_out,
                                                 const float* __restrict__ pmax,
                                                 const int* __restrict__ pidx,
                                                 int mode, int first) {
  __shared__ float rks[32][193];                  // 24.7 KB, conflict-free
  __shared__ __align__(16) float hs[8][RKS];      // 6.1 KB, float4-readable
  __shared__ float xs[8 * 32];
  __shared__ float bs[32];
  __shared__ int   tk[8];
  __shared__ float pv[8 * NTL];
  __shared__ int   pi[8 * NTL];
  __shared__ float cbv[8][4];
  __shared__ int   cbi[8][4];
  __shared__ float gb[32 * 8];

  const int tid = threadIdx.x;
  const int c0 = blockIdx.x * 8;
  const int m0 = blockIdx.y * 8;

  if (mode) {
    if (first) {
      if (tid < 8) tk[tid] = START_;
    } else {
      for (int i = tid; i < 8 * NTL; i += 256) {
        int row = i >> 6, s = i & (NTL - 1);
        pv[i] = pmax[(size_t)(m0 + row) * NTL + s];
        pi[i] = pidx[(size_t)(m0 + row) * NTL + s];
      }
      __syncthreads();
      if (tid < 32) {   // row = tid>>2, chunk = tid&3: s in [16c,16c+16)
        int row = tid >> 2, cch = tid & 3;
        int base = row * NTL + cch * 16;
        float bv = pv[base]; int bi = pi[base];
        for (int s = 1; s < 16; ++s) {
          float v = pv[base + s]; int ii = pi[base + s];
          if (v > bv || (v == bv && ii < bi)) { bv = v; bi = ii; }
        }
        cbv[row][cch] = bv; cbi[row][cch] = bi;
      }
      __syncthreads();
      if (tid < 8) {    // combine chunks ascending -> exact tie-break
        float bv = cbv[tid][0]; int bi = cbi[tid][0];
        for (int cch = 1; cch < 4; ++cch) {
          float v = cbv[tid][cch]; int ii = cbi[tid][cch];
          if (v > bv || (v == bv && ii < bi)) { bv = v; bi = ii; }
        }
        tk[tid] = bi;
      }
    }
    __syncthreads();
  }

  // stage rk slice (32 gate cols x 192 k) from rkT — fully coalesced float4
  for (int i = tid; i < 32 * 48; i += 256) {
    int qq = i / 48, kq = (i - qq * 48) * 4;
    int jj2 = c0 + (qq & 7), g = qq >> 3;
    float4 v = {0, 0, 0, 0};
    if (jj2 < H_) v = *(const float4*)(rkT + (size_t)(jj2 + H_ * g) * RKS + kq);
    rks[qq][kq]     = v.x; rks[qq][kq + 1] = v.y;
    rks[qq][kq + 2] = v.z; rks[qq][kq + 3] = v.w;
  }
  // stage h rows (coalesced read, padded rows for aligned float4 re-read)
  for (int i = tid; i < 8 * H_; i += 256) {
    int r = i / H_, k = i - r * H_;
    hs[r][k] = h_in[(size_t)m0 * H_ + i];
  }
  // stage x gate values and bias for this block's 32 gate columns
  {
    int i = tid;   // 8*32 = 256: exactly one per thread
    int row = i >> 5, q = i & 31;
    int jj = c0 + (q & 7);
    int jg = jj + H_ * (q >> 3);
    float xv = 0.0f;
    if (jj < H_) {
      const float* xrow = mode ? (xk + (size_t)tk[row] * FH_)
                               : (xk + (size_t)(m0 + row) * FH_);
      xv = xrow[jg];
    }
    xs[i] = xv;
  }
  if (tid < 32) {
    int jj = c0 + (tid & 7);
    bs[tid] = (jj < H_) ? bias[jj + H_ * (tid >> 3)] : 0.0f;
  }
  __syncthreads();

  // recurrent dot: thread = (gate-col slot q, row rg); 1 row each.
  // rks banks (q+k)%32 distinct per q -> conflict-free; hs half-wave broadcast.
  const int q = tid & 31, rg = tid >> 5;
  const int jj = c0 + (q & 7);
  float a0 = 0.0f;
  if (jj < H_) {
    const float* rr = rks[q];
    const float* hp = hs[rg];
    int k = 0;
    for (; k < 188; k += 4) {
      float4 hv = *(const float4*)(hp + k);
      a0 = fmaf(hv.x, rr[k    ], a0);
      a0 = fmaf(hv.y, rr[k + 1], a0);
      a0 = fmaf(hv.z, rr[k + 2], a0);
      a0 = fmaf(hv.w, rr[k + 3], a0);
    }
    for (; k < H_; ++k) a0 = fmaf(hp[k], rr[k], a0);
  }
  gb[q * 8 + rg] = a0;
  __syncthreads();

  // pointwise LSTM update for (8 cols x 8 rows)
  if (tid < 64) {
    int cc = tid & 7, row = tid >> 3;
    int jc = c0 + cc;
    if (jc < H_) {
      float gi = gb[(cc     ) * 8 + row] + xs[row * 32 + cc     ] + bs[cc];
      float gf = gb[( 8 + cc) * 8 + row] + xs[row * 32 +  8 + cc] + bs[ 8 + cc];
      float gg = gb[(16 + cc) * 8 + row] + xs[row * 32 + 16 + cc] + bs[16 + cc];
      float go = gb[(24 + cc) * 8 + row] + xs[row * 32 + 24 + cc] + bs[24 + cc];
      float co = c_in[(size_t)(m0 + row) * H_ + jc];
      float cn = sigf(gf) * co + sigf(gi) * tanhf(gg);
      float hn = sigf(go) * tanhf(cn);
      c_out[(size_t)(m0 + row) * H_ + jc] = cn;
      h_out[(size_t)(m0 + row) * H_ + jc] = hn;
    }
  }
}

// ---------------------------------------------------------------------------
// logits = h @ WP + out_b ; out[:, t, :]; per-(row, col-tile) argmax partials.
// Tile 16 rows x 128 cols, grid (64, B/16) = 1024 blocks -> 4 blocks/CU
// (was 2: latency-bound k-loop needs waves). Explicit 2-deep WP prefetch so
// the L2 load stream runs ahead of the FMAs. Thread = (cq=tid&31: 4 cols,
// ro=tid>>5: rows {m0+2ro, m0+2ro+1}). Per-output k-chain unchanged ->
// bitwise-identical logits.
// ---------------------------------------------------------------------------
__global__ __launch_bounds__(256) void logits_argmax(const float* __restrict__ h,
                                                     const float* __restrict__ wp,
                                                     const float* __restrict__ ob,
                                                     float* __restrict__ out, int t,
                                                     float* __restrict__ pmax,
                                                     int* __restrict__ pidx) {
  __shared__ __align__(16) float AT[H_ * 20];   // [k][20-pad r]
  const int tid = threadIdx.x;
  const int n0 = blockIdx.x * 128;
  const int m0 = blockIdx.y * 16;
  for (int i = tid; i < 16 * H_; i += 256) {
    int r = i / H_, k = i - r * H_;
    AT[k * 20 + r] = h[(size_t)m0 * H_ + i];
  }
  __syncthreads();

  const int cq = tid & 31;   // col quad within tile
  const int ro = tid >> 5;   // row pair (0..7)
  const int j = n0 + cq * 4;
  const float* wc = wp + j;
  const float* at = AT + ro * 2;
  float4 acc0 = {0,0,0,0}, acc1 = {0,0,0,0};

#define LFMA(AK, WV) { \
    float2 a_ = *(const float2*)(at + (AK) * 20); \
    acc0.x = fmaf(a_.x, WV.x, acc0.x); acc0.y = fmaf(a_.x, WV.y, acc0.y); \
    acc0.z = fmaf(a_.x, WV.z, acc0.z); acc0.w = fmaf(a_.x, WV.w, acc0.w); \
    acc1.x = fmaf(a_.y, WV.x, acc1.x); acc1.y = fmaf(a_.y, WV.y, acc1.y); \
    acc1.z = fmaf(a_.y, WV.z, acc1.z); acc1.w = fmaf(a_.y, WV.w, acc1.w); }

  float4 w0 = *(const float4*)(wc);                       // k = 0
  int k = 0;
  for (; k < 190; k += 2) {
    float4 w1 = *(const float4*)(wc + (size_t)(k + 1) * VP_);
    LFMA(k, w0)
    w0 = *(const float4*)(wc + (size_t)(k + 2) * VP_);    // k+2 <= 190
    LFMA(k + 1, w1)
  }
  LFMA(190, w0)
#undef LFMA

  float bias4[4];
#pragma unroll
  for (int u = 0; u < 4; ++u) bias4[u] = (j + u < V_) ? ob[j + u] : 0.0f;
  const bool tile_full = (n0 + 128 <= V_);   // only blockIdx.x==63 is partial
#pragma unroll
  for (int rr = 0; rr < 2; ++rr) {
    const int b = m0 + ro * 2 + rr;
    float4 acc = rr ? acc1 : acc0;
    float v[4] = {acc.x + bias4[0], acc.y + bias4[1],
                  acc.z + bias4[2], acc.w + bias4[3]};
    float* orow = out + ((size_t)b * T_ + t) * V_ + j;
    if (tile_full) {
      orow[0] = v[0]; orow[1] = v[1]; orow[2] = v[2]; orow[3] = v[3];
    } else {
#pragma unroll
      for (int u = 0; u < 4; ++u)
        if (j + u < V_) orow[u] = v[u];
    }
    float bv = -INFINITY; int bi = 0;
#pragma unroll
    for (int u = 0; u < 4; ++u)
      if (j + u < V_ && v[u] > bv) { bv = v[u]; bi = j + u; }
    // reduce across the 32 col-lanes of this half-wave (rows never cross)
#pragma unroll
    for (int off = 1; off < 32; off <<= 1) {
      float ov = __shfl_xor(bv, off, 64);
      int   oi = __shfl_xor(bi, off, 64);
      if (ov > bv || (ov == bv && oi < bi)) { bv = ov; bi = oi; }
    }
    if ((tid & 31) == 0) {
      pmax[(size_t)b * NTL + blockIdx.x] = bv;
      pidx[(size_t)b * NTL + blockIdx.x] = bi;
    }
  }
}

// ---------------------------------------------------------------------------
// latent: mu/sigma/z from h_enc, then h0 = c0 = z @ init_w + init_b
// (round-0 proven) grid B/4 blocks x 64 threads.
// ---------------------------------------------------------------------------
__global__ __launch_bounds__(64) void latent_k(const float* __restrict__ h,
                                               const float* __restrict__ eps,
                                               const float* __restrict__ mu_w,
                                               const float* __restrict__ mu_b,
                                               const float* __restrict__ sig_w,
                                               const float* __restrict__ sig_b,
                                               const float* __restrict__ iw,
                                               const float* __restrict__ ib,
                                               float* __restrict__ h0,
                                               float* __restrict__ c0) {
  __shared__ float zs[4 * Z_];
  const int tid = threadIdx.x;
  const int m0 = blockIdx.x * 4;
  if (tid < 4 * Z_) {
    int row = tid / Z_, qz = tid - row * Z_;
    const float* hr = h + (size_t)(m0 + row) * H_;
    float mu = mu_b[qz], sg = sig_b[qz];
    for (int k = 0; k < H_; ++k) {
      float hv = hr[k];
      mu = fmaf(hv, mu_w[k * Z_ + qz], mu);
      sg = fmaf(hv, sig_w[k * Z_ + qz], sg);
    }
    zs[tid] = mu + eps[qz] * sg;
  }
  __syncthreads();
  for (int i = tid; i < 4 * H_; i += 64) {
    int row = i / H_, col = i - row * H_;
    float acc = ib[col];
#pragma unroll
    for (int qz = 0; qz < Z_; ++qz)
      acc = fmaf(zs[row * Z_ + qz], iw[qz * H_ + col], acc);
    h0[(size_t)(m0 + row) * H_ + col] = acc;
    c0[(size_t)(m0 + row) * H_ + col] = acc;
  }
}

// ---------------------------------------------------------------------------
extern "C" void kernel_launch(void* const* d_in, const int* in_sizes, int n_in,
                              void* d_out, int out_size, void* d_ws, size_t ws_size,
                              hipStream_t stream) {
  const int*   inputs = (const int*)  d_in[0];
  const float* eps    = (const float*)d_in[1];
  const float* emb    = (const float*)d_in[2];
  const float* inf_k  = (const float*)d_in[3];
  const float* inf_rk = (const float*)d_in[4];
  const float* inf_b  = (const float*)d_in[5];
  const float* mu_w   = (const float*)d_in[6];
  const float* mu_b   = (const float*)d_in[7];
  const float* sig_w  = (const float*)d_in[8];
  const float* sig_b  = (const float*)d_in[9];
  const float* init_w = (const float*)d_in[10];
  const float* init_b = (const float*)d_in[11];
  const float* gen_k  = (const float*)d_in[12];
  const float* gen_rk = (const float*)d_in[13];
  const float* gen_b  = (const float*)d_in[14];
  const float* out_w  = (const float*)d_in[15];
  const float* out_b  = (const float*)d_in[16];
  float* out = (float*)d_out;

  const int B = in_sizes[0] / T_;        // 256
  const int BH = B * H_;

  float* ws = (float*)d_ws;
  size_t off = 0;
  float* EK = ws + off; off += (size_t)V_ * FH_;        // emb @ gen_k
  float* XK = ws + off; off += (size_t)T_ * B * FH_;    // gathered emb @ inf_k
  float* WP = ws + off; off += (size_t)H_ * VP_;        // padded out_w
  float* rkT = ws + off; off += (size_t)2 * FH_ * RKS;  // rkT[inf|gen][764][192]
  float* hbase = ws + off; off += (size_t)8 * BH;       // he0 ce0 he1 ce1 hd0 cd0 hd1 cd1
  float* he[2] = {hbase + 0 * BH, hbase + 2 * BH};
  float* ce[2] = {hbase + 1 * BH, hbase + 3 * BH};
  float* hd[2] = {hbase + 4 * BH, hbase + 6 * BH};
  float* cd[2] = {hbase + 5 * BH, hbase + 7 * BH};
  float* pmax = ws + off; off += (size_t)B * NTL;
  int*   pidx = (int*)(ws + off); off += (size_t)B * NTL;
  float* rkT_inf = rkT;
  float* rkT_gen = rkT + (size_t)FH_ * RKS;

  // zero initial encoder state (he[0], ce[0] are contiguous)
  hipMemsetAsync(hbase, 0, (size_t)2 * BH * sizeof(float), stream);

  // one-time parallel precomputes
  prep_w<<<(H_ * VP_ + 2 * FH_ * RKS + 255) / 256, 256, 0, stream>>>(
      out_w, inf_rk, gen_rk, WP, rkT);
  gemm_ew<<<dim3(3, (V_ + 15) / 16), 256, 0, stream>>>(emb, gen_k, EK, V_, nullptr, 0, B);
  gemm_ew<<<dim3(3, (T_ * B) / 16), 256, 0, stream>>>(emb, inf_k, XK, T_ * B, inputs, 1, B);

  // encoder
  for (int t = 0; t < T_; ++t) {
    lstm_step<<<dim3(24, B / 8), 256, 0, stream>>>(
        XK + (size_t)t * B * FH_, rkT_inf, inf_b,
        he[t & 1], ce[t & 1], he[(t + 1) & 1], ce[(t + 1) & 1],
        nullptr, nullptr, 0, 0);
  }

  // latent -> decoder initial state (h = c = init_state)
  latent_k<<<B / 4, 64, 0, stream>>>(he[T_ & 1], eps, mu_w, mu_b, sig_w, sig_b,
                                     init_w, init_b, hd[0], cd[0]);

  // autoregressive decoder
  for (int t = 0; t < T_; ++t) {
    lstm_step<<<dim3(24, B / 8), 256, 0, stream>>>(
        EK, rkT_gen, gen_b,
        hd[t & 1], cd[t & 1], hd[(t + 1) & 1], cd[(t + 1) & 1],
        pmax, pidx, 1, (t == 0) ? 1 : 0);
    logits_argmax<<<dim3(NTL, B / 16), 256, 0, stream>>>(
        hd[(t + 1) & 1], WP, out_b, out, t, pmax, pidx);
  }
}